// Round 1
// baseline (155.378 us; speedup 1.0000x reference)
//
#include <hip/hip_runtime.h>
#include <hip/hip_bf16.h>

namespace {
constexpr int kB = 8;
constexpr int kC = 64;
constexpr int kH = 48;
constexpr int kW = 48;
constexpr int kS = kH * kW;          // 2304
constexpr float kEps = 1.1920929e-07f;
// 0.25 (1/sqrt(head_dim)) * log2(e): lets attention use raw v_exp_f32 (2^x)
constexpr float kQScale = 0.25f * 1.4426950408889634f;
}

typedef __attribute__((ext_vector_type(8))) short short8;   // 8 bf16 (4 VGPR)
typedef __attribute__((ext_vector_type(4))) float f32x4;

// fp32 -> bf16 (round-nearest-even), bit-level
__device__ __forceinline__ short f2bf(float x) {
  unsigned u = __float_as_uint(x);
  u += 0x7fffu + ((u >> 16) & 1u);
  return (short)(u >> 16);
}
__device__ __forceinline__ float bf2f(short s) {
  return __uint_as_float(((unsigned)(unsigned short)s) << 16);
}
__device__ __forceinline__ float fexp2(float x) {
  return __builtin_amdgcn_exp2f(x);   // v_exp_f32 (2^x)
}

// ---------------------------------------------------------------------------
// F1: fused prep (unchanged).
// ---------------------------------------------------------------------------
__global__ __launch_bounds__(256) void fused_prep(
    const float* __restrict__ q, const float* __restrict__ k,
    const float* __restrict__ v, const float* __restrict__ wq,
    const float* __restrict__ wk, const float* __restrict__ conv_w,
    short* __restrict__ qt, short* __restrict__ kt, short* __restrict__ vt,
    short* __restrict__ wqb3, short* __restrict__ wkb3, short* __restrict__ wt3) {
  const int blk = blockIdx.x;
  if (blk < 576) {
    __shared__ float tile[64][65];
    const int zz = blk / 36;         // b*2 + which
    const int bx = blk % 36;
    const int b = zz >> 1;
    const float* src = (zz & 1) ? k : q;
    short* dst = (zz & 1) ? kt : qt;
    const int s0 = bx * 64;
    const int tx = threadIdx.x & 63;
    const int ty = threadIdx.x >> 6;
#pragma unroll
    for (int r = 0; r < 16; ++r) {
      int c = r * 4 + ty;
      tile[c][tx] = src[((size_t)b * kC + c) * kS + s0 + tx];
    }
    __syncthreads();
#pragma unroll
    for (int r = 0; r < 16; ++r) {
      int s = r * 4 + ty;
      dst[((size_t)b * kS + s0 + s) * kC + tx] = f2bf(tile[tx][s]);
    }
  } else if (blk < 1728) {
    int idx = ((blk - 576) * 256 + threadIdx.x) * 4;
    float4 x = *reinterpret_cast<const float4*>(v + idx);
    int2 o;
    o.x = ((int)(unsigned short)f2bf(x.y) << 16) | (unsigned short)f2bf(x.x);
    o.y = ((int)(unsigned short)f2bf(x.w) << 16) | (unsigned short)f2bf(x.z);
    *reinterpret_cast<int2*>(vt + idx) = o;
  } else {
    int idx = (blk - 1728) * 256 + threadIdx.x;
    if (idx < 4096) {
      int j = idx & 7, Lw = (idx >> 3) & 63, slab = idx >> 9;
      int nt = slab & 3, kh = slab >> 2;
      int e = nt * 16 + (Lw & 15), c = kh * 32 + (Lw >> 4) * 8 + j;
      wqb3[idx] = f2bf(wq[e * 64 + c]);
    } else if (idx < 8192) {
      int i2 = idx - 4096;
      int j = i2 & 7, Lw = (i2 >> 3) & 63, slab = i2 >> 9;
      int nt = slab & 3, kh = slab >> 2;
      int e = nt * 16 + (Lw & 15), c = kh * 32 + (Lw >> 4) * 8 + j;
      wkb3[i2] = f2bf(wk[e * 64 + c]);
    } else {
      int i3 = idx - 8192;   // < 36864
      int j = i3 & 7, Lw = (i3 >> 3) & 63, slab = i3 >> 9;   // 0..71
      int nt = slab & 3, kh = (slab >> 2) & 1, tap = slab >> 3;
      int co = nt * 16 + (Lw & 15), ci = kh * 32 + (Lw >> 4) * 8 + j;
      wt3[i3] = f2bf(conv_w[co * 576 + ci * 9 + tap]);
    }
  }
}

// ---------------------------------------------------------------------------
// F2: fused q/k projection GEMMs. Only change: q-path epilogue scale now
// folds log2(e) so attention can use raw v_exp_f32.
// ---------------------------------------------------------------------------
__global__ __launch_bounds__(256) void fused_qk_gemm(
    const short* __restrict__ qt, const short* __restrict__ kt,
    const short* __restrict__ wt3, const short* __restrict__ wqb3,
    const short* __restrict__ wkb3,
    const float* __restrict__ nq_w, const float* __restrict__ nk_w,
    const float* __restrict__ bq, const float* __restrict__ bk,
    short* __restrict__ qp, short* __restrict__ kp) {
  __shared__ __align__(16) short Qs[164][72];   // q: halo tile / k: 64-row tile
  __shared__ __align__(16) short ln[4][16][80];
  const int blk = blockIdx.x;
  const int t = threadIdx.x;
  const int ws = t >> 6;
  const int L = t & 63;
  const int quad = L >> 4;
  const int l16 = L & 15;
  const short8 zero8 = {0, 0, 0, 0, 0, 0, 0, 0};

  if (blk < 288) {
    // ---- q path ----
    const int b = blk / 36;
    const int S0 = (blk % 36) * 64;
    const int sBase = S0 + ws * 16;
    const int s = sBase + l16;
    const int h = s / kW, w = s % kW;

    const short* qtb = qt + (size_t)b * kS * kC;
#pragma unroll
    for (int it = 0; it < 6; ++it) {
      int idx = it * 256 + t;
      if (idx < 164 * 8) {
        int r = idx >> 3, sg = idx & 7;
        int srow = S0 - 49 + r;
        srow = srow < 0 ? 0 : (srow >= kS ? kS - 1 : srow);
        *reinterpret_cast<int4*>(&Qs[r][sg * 8]) =
            *reinterpret_cast<const int4*>(qtb + (size_t)srow * kC + sg * 8);
      }
    }
    __syncthreads();

    const int baseLocal = ws * 16 + l16 + 49;
    f32x4 acc[4] = {{0.f, 0.f, 0.f, 0.f}, {0.f, 0.f, 0.f, 0.f},
                    {0.f, 0.f, 0.f, 0.f}, {0.f, 0.f, 0.f, 0.f}};
#pragma unroll
    for (int tap = 0; tap < 9; ++tap) {
      const int dh = tap / 3 - 1, dw = tap % 3 - 1;
      const bool valid = (unsigned)(h + dh) < (unsigned)kH &&
                         (unsigned)(w + dw) < (unsigned)kW;
      const int local = baseLocal + dh * kW + dw;
#pragma unroll
      for (int kh = 0; kh < 2; ++kh) {
        short8 af = *reinterpret_cast<const short8*>(&Qs[local][kh * 32 + quad * 8]);
        af = valid ? af : zero8;
        const short* wb = wt3 + ((tap * 2 + kh) * 4) * 512 + L * 8;
#pragma unroll
        for (int nt = 0; nt < 4; ++nt) {
          short8 bf = *reinterpret_cast<const short8*>(wb + nt * 512);  // coalesced
          acc[nt] = __builtin_amdgcn_mfma_f32_16x16x32_bf16(af, bf, acc[nt], 0, 0, 0);
        }
      }
    }
    float rstd[4];
#pragma unroll
    for (int reg = 0; reg < 4; ++reg) {
      float pr = acc[0][reg] * acc[0][reg] + acc[1][reg] * acc[1][reg]
               + acc[2][reg] * acc[2][reg] + acc[3][reg] * acc[3][reg];
      pr += __shfl_xor(pr, 1, 64);
      pr += __shfl_xor(pr, 2, 64);
      pr += __shfl_xor(pr, 4, 64);
      pr += __shfl_xor(pr, 8, 64);
      rstd[reg] = rsqrtf(pr * (1.0f / kC) + kEps);
    }
#pragma unroll
    for (int nt = 0; nt < 4; ++nt) {
      float g = nq_w[nt * 16 + l16];
#pragma unroll
      for (int reg = 0; reg < 4; ++reg) {
        ln[ws][quad * 4 + reg][nt * 16 + l16] = f2bf(acc[nt][reg] * rstd[reg] * g);
      }
    }
    __syncthreads();
    f32x4 acc2[4] = {{0.f, 0.f, 0.f, 0.f}, {0.f, 0.f, 0.f, 0.f},
                     {0.f, 0.f, 0.f, 0.f}, {0.f, 0.f, 0.f, 0.f}};
#pragma unroll
    for (int kh = 0; kh < 2; ++kh) {
      short8 af = *reinterpret_cast<const short8*>(&ln[ws][l16][kh * 32 + quad * 8]);
      const short* wb = wqb3 + (kh * 4) * 512 + L * 8;
#pragma unroll
      for (int nt = 0; nt < 4; ++nt) {
        short8 bf = *reinterpret_cast<const short8*>(wb + nt * 512);   // coalesced
        acc2[nt] = __builtin_amdgcn_mfma_f32_16x16x32_bf16(af, bf, acc2[nt], 0, 0, 0);
      }
    }
#pragma unroll
    for (int nt = 0; nt < 4; ++nt) {
      const int e = nt * 16 + l16;
      float bias = bq[e];
#pragma unroll
      for (int reg = 0; reg < 4; ++reg) {
        qp[((size_t)b * kS + sBase + quad * 4 + reg) * kC + e] =
            f2bf((acc2[nt][reg] + bias) * kQScale);
      }
    }
  } else {
    // ---- k path ----
    const int idx = blk - 288;
    const int b = idx / 36;
    const int S0 = (idx % 36) * 64;
    const int sBase = S0 + ws * 16;

    const short* ktb = kt + ((size_t)b * kS + S0) * kC;
#pragma unroll
    for (int it = 0; it < 2; ++it) {
      int r = it * 32 + (t >> 3), sg = t & 7;
      *reinterpret_cast<int4*>(&Qs[r][sg * 8]) =
          *reinterpret_cast<const int4*>(ktb + (size_t)r * kC + sg * 8);
    }
    __syncthreads();

    short8 af0 = *reinterpret_cast<const short8*>(&Qs[ws * 16 + l16][quad * 8]);
    short8 af1 = *reinterpret_cast<const short8*>(&Qs[ws * 16 + l16][32 + quad * 8]);

    float xs[16];
#pragma unroll
    for (int j = 0; j < 8; ++j) { xs[j] = bf2f(af0[j]); xs[8 + j] = bf2f(af1[j]); }
    float sum = 0.f;
#pragma unroll
    for (int j = 0; j < 16; ++j) sum = fmaf(xs[j], xs[j], sum);
    sum += __shfl_xor(sum, 16, 64);
    sum += __shfl_xor(sum, 32, 64);
    float rstd = rsqrtf(sum * (1.0f / kC) + kEps);

    const float* n0 = nk_w + quad * 8;
#pragma unroll
    for (int j = 0; j < 8; ++j) {
      af0[j] = f2bf(xs[j] * rstd * n0[j]);
      af1[j] = f2bf(xs[8 + j] * rstd * n0[32 + j]);
    }

    f32x4 acc[4] = {{0.f, 0.f, 0.f, 0.f}, {0.f, 0.f, 0.f, 0.f},
                    {0.f, 0.f, 0.f, 0.f}, {0.f, 0.f, 0.f, 0.f}};
#pragma unroll
    for (int nt = 0; nt < 4; ++nt) {
      short8 bf0 = *reinterpret_cast<const short8*>(
          wkb3 + (0 * 4 + nt) * 512 + L * 8);
      short8 bf1 = *reinterpret_cast<const short8*>(
          wkb3 + (1 * 4 + nt) * 512 + L * 8);
      acc[nt] = __builtin_amdgcn_mfma_f32_16x16x32_bf16(af0, bf0, acc[nt], 0, 0, 0);
      acc[nt] = __builtin_amdgcn_mfma_f32_16x16x32_bf16(af1, bf1, acc[nt], 0, 0, 0);
    }
#pragma unroll
    for (int nt = 0; nt < 4; ++nt) {
      const int e = nt * 16 + l16;
      float bias = bk[e];
#pragma unroll
      for (int reg = 0; reg < 4; ++reg) {
        kp[((size_t)b * kS + sBase + quad * 4 + reg) * kC + e] =
            f2bf(acc[nt][reg] + bias);
      }
    }
  }
}

// ---------------------------------------------------------------------------
// K3: flash attention, HEAD-PAIR SPLIT. grid 1152: b = blk&7, idx = blk>>3,
// hp = idx&1 (heads 2hp..2hp+1), i0 = (idx>>1)*32. Each block sweeps all j
// for its 2 heads: softmax denominators are per-head-complete, so the block
// emits a fully normalized partial output; the two head-pair blocks combine
// via atomicAdd (out pre-zeroed by hipMemsetAsync; fp32 add commutes →
// deterministic). K staging halves to the pair's 32-d window → LDS 29.4 KB
// → 5 blocks/CU. Scores come out pre-scaled by log2(e) (qp fold) → raw
// v_exp_f32. Zero-LDS P transpose via K-row permutation kept unchanged.
// ---------------------------------------------------------------------------
__global__ __launch_bounds__(256, 5) void attn_flash(
    const short* __restrict__ qp, const short* __restrict__ kp,
    const short* __restrict__ vt, float* __restrict__ out) {
  __shared__ __align__(16) short Kt[2][64][40];   // K rows (hp window) PERMUTED per 32-group
  __shared__ __align__(16) short Vt[2][64][72];   // V^T rows, unpermuted
  __shared__ float pl[4][16][2];   // [ws][i16][hl]
  __shared__ float Li[32][2];      // 0.25 / l

  float* slabF = reinterpret_cast<float*>(&Kt[0][0][0]);  // epilogue alias (4.2KB<10.2KB)

  const int blk = blockIdx.x;
  const int b = blk & 7;           // low bits → all of batch b on one XCD (L2 fit)
  const int idx = blk >> 3;        // 0..143
  const int hp = idx & 1;          // head pair: heads 2hp, 2hp+1 (d window hp*32..+31)
  const int i0 = (idx >> 1) * 32;
  const int t = threadIdx.x;
  const int ws = t >> 6;
  const int isub = ws & 1;
  const int jhalf = ws >> 1;
  const int jbase = jhalf * 32;
  const int L = t & 63;
  const int quad = L >> 4;
  const int l16 = L & 15;

  const f32x4 zc = {0.f, 0.f, 0.f, 0.f};
  const short8 z8 = {0, 0, 0, 0, 0, 0, 0, 0};

  // Q window (B operand, K=32 = this head pair's d window): row i, dims hp*32+quad*8..+7
  const short* qrow = qp + ((size_t)b * kS + i0 + isub * 16 + l16) * kC + hp * 32;
  const short8 qw = *reinterpret_cast<const short8*>(qrow + quad * 8);
  const bool lo = quad < 2;
  const short8 qm[2] = {lo ? qw : z8, lo ? z8 : qw};   // local heads 0,1 of the pair

  // staging geometry. K: 64 rows × 32 shorts (window) in ONE pass: 4 lanes/row.
  const int rK = t >> 2;    // 0..63
  const int segK = t & 3;
  // V: 2 passes of 32 rows × 64 shorts: 8 lanes/row.
  const int r8i = t >> 3;   // 0..31
  const int seg = t & 7;
  const short* kg = kp + (size_t)b * kS * kC + hp * 32;
  const short* vg = vt + (size_t)b * kC * kS;

  // K destination row (permuted): j -> p32 bits: (c=bit2)*16 + (q=bits3-4)*4 + (r=bits0-1)
  const int p32 = rK & 31;
  const int prowK =
      (rK & 32) | ((p32 & 4) << 2) | (((p32 >> 3) & 3) << 2) | (p32 & 3);

  int4 kreg, vreg[2];
  kreg = *reinterpret_cast<const int4*>(kg + (size_t)rK * kC + segK * 8);
#pragma unroll
  for (int pass = 0; pass < 2; ++pass)
    vreg[pass] = *reinterpret_cast<const int4*>(
        vg + (size_t)(pass * 32 + r8i) * kS + seg * 8);
  *reinterpret_cast<int4*>(&Kt[0][prowK][segK * 8]) = kreg;
#pragma unroll
  for (int pass = 0; pass < 2; ++pass)
    *reinterpret_cast<int4*>(&Vt[0][pass * 32 + r8i][seg * 8]) = vreg[pass];
  __syncthreads();

  f32x4 U[2][4];   // [hl][dtile]: lane holds d=dtile*16+quad*4+reg, i=l16
#pragma unroll
  for (int hl = 0; hl < 2; ++hl)
#pragma unroll
    for (int d = 0; d < 4; ++d) U[hl][d] = zc;
  float lh[2] = {0.f, 0.f};

  for (int jt = 0; jt < kS / 64; ++jt) {
    const int buf = jt & 1;
    const bool more = (jt + 1) < kS / 64;
    if (more) {
      const int jn = (jt + 1) * 64;
      kreg = *reinterpret_cast<const int4*>(
          kg + (size_t)(jn + rK) * kC + segK * 8);
#pragma unroll
      for (int pass = 0; pass < 2; ++pass)
        vreg[pass] = *reinterpret_cast<const int4*>(
            vg + (size_t)(pass * 32 + r8i) * kS + jn + seg * 8);
    }

    // K A-frags (permuted rows): [chunk]; V^T A-frags per dtile
    short8 kf[2];
#pragma unroll
    for (int c = 0; c < 2; ++c)
      kf[c] = *reinterpret_cast<const short8*>(
          &Kt[buf][jbase + c * 16 + l16][quad * 8]);
    short8 vf[4];
#pragma unroll
    for (int d = 0; d < 4; ++d)
      vf[d] = *reinterpret_cast<const short8*>(
          &Vt[buf][d * 16 + l16][jbase + quad * 8]);

#pragma unroll
    for (int hl = 0; hl < 2; ++hl) {
      // chunk c result reg r = e(i=l16, j = quad*8 + c*4 + r)  [permutation]
      f32x4 s0 = __builtin_amdgcn_mfma_f32_16x16x32_bf16(kf[0], qm[hl], zc, 0, 0, 0);
      f32x4 s1 = __builtin_amdgcn_mfma_f32_16x16x32_bf16(kf[1], qm[hl], zc, 0, 0, 0);
      float e0 = fexp2(s0[0]), e1 = fexp2(s0[1]);
      float e2 = fexp2(s0[2]), e3 = fexp2(s0[3]);
      float f0 = fexp2(s1[0]), f1 = fexp2(s1[1]);
      float f2 = fexp2(s1[2]), f3 = fexp2(s1[3]);
      lh[hl] += ((e0 + e1) + (e2 + e3)) + ((f0 + f1) + (f2 + f3));
      // pack: pf[idx] = e(i=l16, j=quad*8+idx) == PV B-frag, no LDS round-trip
      union { __hip_bfloat162 h2[4]; short8 s8; } cv;
      cv.h2[0] = __float22bfloat162_rn(make_float2(e0, e1));
      cv.h2[1] = __float22bfloat162_rn(make_float2(e2, e3));
      cv.h2[2] = __float22bfloat162_rn(make_float2(f0, f1));
      cv.h2[3] = __float22bfloat162_rn(make_float2(f2, f3));
#pragma unroll
      for (int d = 0; d < 4; ++d)
        U[hl][d] = __builtin_amdgcn_mfma_f32_16x16x32_bf16(vf[d], cv.s8, U[hl][d], 0, 0, 0);
    }

    if (more) {
      const int nb = buf ^ 1;
      *reinterpret_cast<int4*>(&Kt[nb][prowK][segK * 8]) = kreg;
#pragma unroll
      for (int pass = 0; pass < 2; ++pass)
        *reinterpret_cast<int4*>(&Vt[nb][pass * 32 + r8i][seg * 8]) = vreg[pass];
    }
    __syncthreads();
  }

  // ---- epilogue ----
#pragma unroll
  for (int hl = 0; hl < 2; ++hl) {
    lh[hl] += __shfl_xor(lh[hl], 16, 64);
    lh[hl] += __shfl_xor(lh[hl], 32, 64);
  }
  if (quad == 0) {
#pragma unroll
    for (int hl = 0; hl < 2; ++hl) pl[ws][l16][hl] = lh[hl];
  }
  __syncthreads();
  if (t < 64) {
    const int i = t >> 1, h2 = t & 1;    // i 0..31 (local sub-row)
    Li[i][h2] = 0.25f / (pl[i >> 4][i & 15][h2] + pl[(i >> 4) + 2][i & 15][h2]);
  }
  __syncthreads();
  float c2[2];
#pragma unroll
  for (int hl = 0; hl < 2; ++hl) c2[hl] = Li[isub * 16 + l16][hl];

  // jhalf-pair reduce, one d-tile per phase; slab lane-major (stride 66)
#pragma unroll
  for (int d = 0; d < 4; ++d) {
    if (jhalf == 1) {
#pragma unroll
      for (int hl = 0; hl < 2; ++hl)
#pragma unroll
        for (int reg = 0; reg < 4; ++reg)
          slabF[((isub * 2 + hl) * 4 + reg) * 66 + L] = U[hl][d][reg];
    }
    __syncthreads();
    if (jhalf == 0) {
      float of[4] = {0.f, 0.f, 0.f, 0.f};
#pragma unroll
      for (int hl = 0; hl < 2; ++hl) {
#pragma unroll
        for (int reg = 0; reg < 4; ++reg) {
          float tot = U[hl][d][reg] + slabF[((isub * 2 + hl) * 4 + reg) * 66 + L];
          of[reg] += tot * c2[hl];
        }
      }
      float* op = out + ((size_t)b * kS + i0 + isub * 16 + l16) * kC + d * 16 + quad * 4;
#pragma unroll
      for (int reg = 0; reg < 4; ++reg) atomicAdd(op + reg, of[reg]);
    }
    __syncthreads();
  }
}

// ---------------------------------------------------------------------------
extern "C" void kernel_launch(void* const* d_in, const int* in_sizes, int n_in,
                              void* d_out, int out_size, void* d_ws, size_t ws_size,
                              hipStream_t stream) {
  const float* q      = (const float*)d_in[0];
  const float* k      = (const float*)d_in[1];
  const float* v      = (const float*)d_in[2];
  const float* conv_w = (const float*)d_in[3];
  const float* nq_w   = (const float*)d_in[4];
  const float* nk_w   = (const float*)d_in[5];
  const float* wq     = (const float*)d_in[6];
  const float* bq     = (const float*)d_in[7];
  const float* wk     = (const float*)d_in[8];
  const float* bk     = (const float*)d_in[9];
  float* out = (float*)d_out;

  const size_t N = (size_t)kB * kS * kC;   // 1,179,648
  short* qt   = (short*)d_ws;     // bf16 [b][s][c]
  short* kt   = qt + N;
  short* vt   = kt + N;           // bf16 [b][c][s]
  short* qp   = vt + N;           // bf16 [b][s][64], pre-scaled by 0.25*log2(e)
  short* kp   = qp + N;
  short* wqb3 = kp + N;           // frag-major bf16
  short* wkb3 = wqb3 + 4096;
  short* wt3  = wkb3 + 4096;      // frag-major bf16 [72 slabs][512]

  // head-pair blocks combine via atomicAdd → zero the output first (capturable)
  hipMemsetAsync(d_out, 0, out_size, stream);

  fused_prep<<<1904, 256, 0, stream>>>(q, k, v, wq, wk, conv_w,
                                       qt, kt, vt, wqb3, wkb3, wt3);
  fused_qk_gemm<<<576, 256, 0, stream>>>(qt, kt, wt3, wqb3, wkb3,
                                         nq_w, nk_w, bq, bk, qp, kp);
  attn_flash<<<1152, 256, 0, stream>>>(qp, kp, vt, out);
}